// Round 1
// baseline (688.947 us; speedup 1.0000x reference)
//
#include <hip/hip_runtime.h>
#include <hip/hip_bf16.h>

#define NROWS 65536
#define KDIM  1024
#define NOUT  1024
#define NTYPE 8

typedef __attribute__((ext_vector_type(8))) short bf16x8;
typedef __attribute__((ext_vector_type(4))) float f32x4;

// RNE fp32 -> bf16 pack (2 values -> 1 dword), ~3 VALU per value
__device__ __forceinline__ unsigned int pk2_rn(float a, float b) {
  unsigned int ua = __float_as_uint(a);
  unsigned int ub = __float_as_uint(b);
  ua += 0x7fffu + ((ua >> 16) & 1u);
  ub += 0x7fffu + ((ub >> 16) & 1u);
  return (ua >> 16) | (ub & 0xffff0000u);
}

__device__ __forceinline__ void async_cp16(const void* g, void* l) {
  __builtin_amdgcn_global_load_lds(
      (const __attribute__((address_space(1))) unsigned int*)g,
      (__attribute__((address_space(3))) unsigned int*)l, 16, 0, 0);
}

// W fp32 [t][k][n]  ->  Wt bf16 [t][n][k], 16B blocks within each 64B k-group
// swizzled: block b stored at b ^ ((n>>1)&3). Fully coalesced both sides.
__global__ void wtrans_kernel(const float* __restrict__ W,
                              unsigned short* __restrict__ Wt) {
  const int ty    = blockIdx.x;
  const int ntile = blockIdx.y;
  const int ks    = blockIdx.z;
  const int n   = ntile * 64 + (threadIdx.x >> 2);
  const int kcs = threadIdx.x & 3;
  const float* src = W + (size_t)ty * (KDIM * NOUT);
  unsigned short* dst = Wt + (size_t)ty * (KDIM * NOUT);
  const int sw = (n >> 1) & 3;
  for (int round = 0; round < 8; ++round) {
    int kc = ks * 32 + round * 4 + kcs;  // 8-element k-chunk index, 0..127
    int k0 = kc * 8;
    float v[8];
#pragma unroll
    for (int j = 0; j < 8; ++j) v[j] = src[(size_t)(k0 + j) * NOUT + n];
    uint4 o;
    o.x = pk2_rn(v[0], v[1]);
    o.y = pk2_rn(v[2], v[3]);
    o.z = pk2_rn(v[4], v[5]);
    o.w = pk2_rn(v[6], v[7]);
    int G  = kc >> 2;
    int bp = (kc & 3) ^ sw;
    *(uint4*)(dst + (size_t)n * KDIM + G * 32 + bp * 8) = o;
  }
}

// 128x128 tile, BK=32, 256 threads (4 waves, 2x2 of 64x64), 16x16x32 bf16 MFMA.
// A (x fp32) staged with inline RNE->bf16; B (Wt bf16) staged via global_load_lds.
// Sorted types: loop t0..t1 (usually one pass), zero-mask A rows not of type t.
__global__ __launch_bounds__(256) void typed_gemm_kernel(
    const float* __restrict__ x, const int* __restrict__ types,
    const unsigned short* __restrict__ Wt, const float* __restrict__ bias,
    float* __restrict__ out) {
  __shared__ unsigned short As[128 * 32];  // [m][32k], swizzled 16B blocks
  __shared__ unsigned short Bs[128 * 32];  // [n][32k], swizzled 16B blocks

  const int tid  = threadIdx.x;
  const int lane = tid & 63;
  const int wave = tid >> 6;
  const int quad = lane >> 4;
  const int l16  = lane & 15;

  const int n0 = blockIdx.x * 128;
  const int m0 = blockIdx.y * 128;

  const int t0 = types[m0];
  const int t1 = types[m0 + 127];
  const bool multi = (t0 != t1);

  // This thread's 4 staged (row, k-chunk) slots are fixed across iterations.
  int srow[4], stype[4], aoff[4];
  const float* agp[4];
#pragma unroll
  for (int r = 0; r < 4; ++r) {
    int idx = r * 256 + tid;
    int m = idx >> 3;        // 0..127
    int kc = idx & 7;        // float4 chunk within BK=32
    srow[r]  = m;
    stype[r] = types[m0 + m];
    int b  = kc >> 1;        // 16B block (8 bf16)
    int h  = kc & 1;         // which half of the block
    int bp = b ^ ((m >> 1) & 3);
    aoff[r] = m * 32 + bp * 8 + h * 4;  // elements
    agp[r]  = x + (size_t)(m0 + m) * KDIM + kc * 4;
  }

  const int mbase = (wave & 1) * 64;
  const int nbase = (wave >> 1) * 64;

  // LDS fragment read offsets (elements), swizzle-corrected
  int ard[4], brd[4];
#pragma unroll
  for (int mt = 0; mt < 4; ++mt) {
    int m = mbase + mt * 16 + l16;
    ard[mt] = m * 32 + (quad ^ ((m >> 1) & 3)) * 8;
  }
#pragma unroll
  for (int nt = 0; nt < 4; ++nt) {
    int n = nbase + nt * 16 + l16;
    brd[nt] = n * 32 + (quad ^ ((n >> 1) & 3)) * 8;
  }

  f32x4 acc[4][4];
#pragma unroll
  for (int i = 0; i < 4; ++i)
#pragma unroll
    for (int j = 0; j < 4; ++j) acc[i][j] = (f32x4){0.f, 0.f, 0.f, 0.f};

  // B async-copy addressing: seg = wave*2+c covers 16 n-rows (64B per row)
  const int brow = lane >> 2;   // row within segment
  const int bchk = lane & 3;    // 16B chunk within 64B row

  for (int t = t0; t <= t1; ++t) {
    const unsigned short* wbase = Wt + (size_t)t * (KDIM * NOUT);
    bool msk[4];
#pragma unroll
    for (int r = 0; r < 4; ++r) msk[r] = (stype[r] == t);

    for (int kb = 0; kb < KDIM; kb += 32) {
      // ---- stage B via global->LDS DMA (raw copy preserves swizzle) ----
      {
        int seg0 = wave * 2;
        int seg1 = seg0 + 1;
        const unsigned short* g0 =
            wbase + (size_t)(n0 + seg0 * 16 + brow) * KDIM + kb + bchk * 8;
        const unsigned short* g1 =
            wbase + (size_t)(n0 + seg1 * 16 + brow) * KDIM + kb + bchk * 8;
        async_cp16(g0, &Bs[seg0 * 512 + lane * 8]);
        async_cp16(g1, &Bs[seg1 * 512 + lane * 8]);
      }
      // ---- stage A: fp32 load, RNE->bf16, type mask, 8B LDS write ----
#pragma unroll
      for (int r = 0; r < 4; ++r) {
        float4 v = *(const float4*)(agp[r] + kb);
        uint2 p;
        p.x = pk2_rn(v.x, v.y);
        p.y = pk2_rn(v.z, v.w);
        if (!msk[r]) { p.x = 0u; p.y = 0u; }
        *(uint2*)(&As[aoff[r]]) = p;
      }
      __syncthreads();

      bf16x8 af[4], bfr[4];
#pragma unroll
      for (int i = 0; i < 4; ++i) af[i] = *(const bf16x8*)(&As[ard[i]]);
#pragma unroll
      for (int i = 0; i < 4; ++i) bfr[i] = *(const bf16x8*)(&Bs[brd[i]]);
#pragma unroll
      for (int mt = 0; mt < 4; ++mt)
#pragma unroll
        for (int nt = 0; nt < 4; ++nt)
          acc[mt][nt] = __builtin_amdgcn_mfma_f32_16x16x32_bf16(
              af[mt], bfr[nt], acc[mt][nt], 0, 0, 0);
      __syncthreads();
    }
  }

  // ---- epilogue: add per-row bias, store fp32 ----
  // C/D layout: col = l16 (+nt*16), row = quad*4+reg (+mt*16)
  float bval[4];
  if (!multi) {
#pragma unroll
    for (int nt = 0; nt < 4; ++nt)
      bval[nt] = bias[t0 * NOUT + n0 + nbase + nt * 16 + l16];
  }
#pragma unroll
  for (int mt = 0; mt < 4; ++mt) {
#pragma unroll
    for (int reg = 0; reg < 4; ++reg) {
      int rl = mbase + mt * 16 + quad * 4 + reg;
      int grow = m0 + rl;
      float* orow = out + (size_t)grow * NOUT + n0 + nbase + l16;
      if (!multi) {
#pragma unroll
        for (int nt = 0; nt < 4; ++nt)
          orow[nt * 16] = acc[mt][nt][reg] + bval[nt];
      } else {
        int ty = types[grow];
#pragma unroll
        for (int nt = 0; nt < 4; ++nt)
          orow[nt * 16] =
              acc[mt][nt][reg] + bias[ty * NOUT + n0 + nbase + nt * 16 + l16];
      }
    }
  }
}

extern "C" void kernel_launch(void* const* d_in, const int* in_sizes, int n_in,
                              void* d_out, int out_size, void* d_ws,
                              size_t ws_size, hipStream_t stream) {
  const float* x     = (const float*)d_in[0];
  const int*   types = (const int*)d_in[1];
  const float* W     = (const float*)d_in[2];
  const float* b     = (const float*)d_in[3];
  float* out = (float*)d_out;
  unsigned short* Wt = (unsigned short*)d_ws;  // 8*1024*1024 bf16 = 16 MB

  // Rebuild Wt every call (d_ws is re-poisoned before each timed launch).
  wtrans_kernel<<<dim3(NTYPE, 16, 4), 256, 0, stream>>>(W, Wt);
  // col-tile fastest => linear id % 8 == col-tile => per-XCD W locality
  typed_gemm_kernel<<<dim3(NOUT / 128, NROWS / 128), 256, 0, stream>>>(
      x, types, Wt, b, out);
}